// Round 6
// baseline (364.850 us; speedup 1.0000x reference)
//
#include <hip/hip_runtime.h>

#define EPSF 1e-6f
#define Bsz 2
#define Tn  512
#define En  1024
#define Hn  256
#define Mtot (Bsz * Tn)          // 1024 rows
#define NBLK 512
typedef unsigned short us_t;
typedef unsigned int   u32_t;

typedef __attribute__((ext_vector_type(8))) short bf16x8;
typedef __attribute__((ext_vector_type(4))) float f32x4;
#define MFMA16(a, b, c) __builtin_amdgcn_mfma_f32_16x16x32_bf16((a), (b), (c), 0, 0, 0)

struct Ptrs {
  const float *x, *w1, *b1, *w2, *b2, *w3, *b3;
  float* out;
  us_t *xb, *w1t, *w2t, *w3t, *A, *Bm, *Yb;
  float *rs, *P;
  u32_t *bar;
};

// ---------------------------------------------------------------------------
__device__ __forceinline__ us_t f2bf(float f) {
  union { float f; u32_t u; } x; x.f = f;
  u32_t r = (x.u + 0x7fffu + ((x.u >> 16) & 1u)) >> 16;   // RNE
  return (us_t)r;
}
__device__ __forceinline__ float bf2f(us_t u) {
  union { u32_t u; float f; } x; x.u = ((u32_t)u) << 16; return x.f;
}
__device__ __forceinline__ uint2 pack4bf(float a, float b, float c, float d) {
  uint2 r;
  r.x = (u32_t)f2bf(a) | ((u32_t)f2bf(b) << 16);
  r.y = (u32_t)f2bf(c) | ((u32_t)f2bf(d) << 16);
  return r;
}
__device__ __forceinline__ float block_reduce_sum_256(float v, float* smem) {
  #pragma unroll
  for (int off = 32; off > 0; off >>= 1) v += __shfl_down(v, off, 64);
  const int wave = threadIdx.x >> 6;
  if ((threadIdx.x & 63) == 0) smem[wave] = v;
  __syncthreads();
  float s = smem[0] + smem[1] + smem[2] + smem[3];
  __syncthreads();
  return s;
}

// ---------------------------------------------------------------------------
// Hand-rolled grid barrier.  Monotonic counter (zeroed by k_zero each call);
// release fence before arrive (L2 writeback), acquire fence for ALL threads
// after (invalidate stale per-XCD L2 / per-CU L1 lines).  Residency is
// guaranteed by the cooperative launch.
// ---------------------------------------------------------------------------
__device__ __forceinline__ void gbar(u32_t* cnt) {
  __syncthreads();
  if (threadIdx.x == 0) {
    __threadfence();                                 // release
    atomicAdd(cnt, 1u);
    while (atomicAdd(cnt, 0u) < (u32_t)NBLK)         // coherent atomic read
      __builtin_amdgcn_s_sleep(2);
  }
  __syncthreads();
  __threadfence();                                   // acquire (all waves)
}

// ---------------------------------------------------------------------------
// Phase 0 unit u (0..1791): u<1024 -> cast x row + rowscale; else transpose
// one 32x32 tile of w1/w2/w3 into [N][K] bf16.
// ---------------------------------------------------------------------------
__device__ __forceinline__ void phase_prep(
    int u, int t, const Ptrs& p, float* red, float (*ts)[33])
{
  if (u < 1024) {
    float4 v = ((const float4*)(p.x + (size_t)u * En))[t];
    float ss = block_reduce_sum_256(v.x*v.x + v.y*v.y + v.z*v.z + v.w*v.w, red);
    if (t == 0) p.rs[u] = rsqrtf(ss * (1.0f / En) + EPSF);
    ((uint2*)(p.xb + (size_t)u * En))[t] = pack4bf(v.x, v.y, v.z, v.w);
    return;
  }
  const int i = u - 1024;
  const float* src; us_t* dst; int R, C, tr, tc;
  if (i < 256)      { src = p.w1; dst = p.w1t; R = 1024; C = 256;  tr = i >> 3;  tc = i & 7; }
  else if (i < 512) { int k = i - 256; src = p.w2; dst = p.w2t; R = 1024; C = 256; tr = k >> 3; tc = k & 7; }
  else              { int k = i - 512; src = p.w3; dst = p.w3t; R = 256; C = 1024; tr = k >> 5; tc = k & 31; }

  __syncthreads();   // guard ts against previous iteration's readers
  const int r = t >> 3, c4 = (t & 7) * 4;
  float4 v = *(const float4*)(src + (size_t)(tr * 32 + r) * C + tc * 32 + c4);
  ts[r][c4 + 0] = v.x; ts[r][c4 + 1] = v.y; ts[r][c4 + 2] = v.z; ts[r][c4 + 3] = v.w;
  __syncthreads();
  float o0 = ts[c4 + 0][r], o1 = ts[c4 + 1][r], o2 = ts[c4 + 2][r], o3 = ts[c4 + 3][r];
  *(uint2*)(dst + (size_t)(tc * 32 + r) * R + tr * 32 + c4) = pack4bf(o0, o1, o2, o3);
}

// ---------------------------------------------------------------------------
// Phase 1 wave unit wg (0..2047): split-K MFMA GEMM, wave tile 32x32, K=256.
// Raw partials -> P[ks][1024][512].
// ---------------------------------------------------------------------------
__device__ __forceinline__ void phase_gemm(int wg, int lane, const Ptrs& p)
{
  const int ks = wg & 3, nt = (wg >> 2) & 15, mt = wg >> 6;
  const int m0 = mt * 32, n0 = nt * 32, k0 = ks * 256;
  const int lg = lane >> 4, lr = lane & 15;

  const us_t* ap0 = p.xb + (size_t)(m0 + lr) * En + k0 + lg * 8;
  const us_t* ap1 = ap0 + 16 * En;
  const us_t* bbase = (n0 < Hn) ? (p.w1t + (size_t)n0 * En)
                                : (p.w2t + (size_t)(n0 - Hn) * En);
  const us_t* bp0 = bbase + (size_t)lr * En + k0 + lg * 8;
  const us_t* bp1 = bp0 + 16 * En;

  f32x4 acc00 = {0.f,0.f,0.f,0.f}, acc01 = acc00, acc10 = acc00, acc11 = acc00;

  #pragma unroll 4
  for (int s = 0; s < 8; ++s) {
    bf16x8 a0 = *(const bf16x8*)(ap0 + s * 32);
    bf16x8 a1 = *(const bf16x8*)(ap1 + s * 32);
    bf16x8 b0 = *(const bf16x8*)(bp0 + s * 32);
    bf16x8 b1 = *(const bf16x8*)(bp1 + s * 32);
    acc00 = MFMA16(a0, b0, acc00);
    acc01 = MFMA16(a0, b1, acc01);
    acc10 = MFMA16(a1, b0, acc10);
    acc11 = MFMA16(a1, b1, acc11);
  }

  float* pw = p.P + ((size_t)ks * Mtot + m0 + lg * 4) * 512 + n0 + lr;
  #pragma unroll
  for (int i = 0; i < 4; ++i) {
    pw[(size_t)i        * 512      ] = acc00[i];
    pw[(size_t)i        * 512 + 16 ] = acc01[i];
    pw[(size_t)(i + 16) * 512      ] = acc10[i];
    pw[(size_t)(i + 16) * 512 + 16 ] = acc11[i];
  }
}

// ---------------------------------------------------------------------------
// Phase 2 wave unit rw (0..2047): combine partials, rs+bias, row-RMSNorm,
// write bf16 A / Bm.
// ---------------------------------------------------------------------------
__device__ __forceinline__ void phase_norm(int rw, int lane, const Ptrs& p)
{
  const int which = rw >> 10, r = rw & 1023;
  const float* bias = which ? p.b2 : p.b1;
  const int h0 = lane * 4;
  const size_t off = (size_t)r * 512 + which * Hn + h0;
  const size_t KS = (size_t)Mtot * 512;

  float4 d0 = *(const float4*)(p.P + off);
  float4 d1 = *(const float4*)(p.P + off + KS);
  float4 d2 = *(const float4*)(p.P + off + 2 * KS);
  float4 d3 = *(const float4*)(p.P + off + 3 * KS);
  const float sc0 = p.rs[r];
  float4 bv = *(const float4*)(bias + h0);
  float vx = (d0.x + d1.x + d2.x + d3.x) * sc0 + bv.x;
  float vy = (d0.y + d1.y + d2.y + d3.y) * sc0 + bv.y;
  float vz = (d0.z + d1.z + d2.z + d3.z) * sc0 + bv.z;
  float vw = (d0.w + d1.w + d2.w + d3.w) * sc0 + bv.w;

  float ss = vx*vx + vy*vy + vz*vz + vw*vw;
  #pragma unroll
  for (int o2 = 32; o2 > 0; o2 >>= 1) ss += __shfl_xor(ss, o2, 64);
  const float sc = rsqrtf(ss * (1.0f / Hn) + EPSF);

  us_t* outp = which ? p.Bm : p.A;
  *(uint2*)(outp + (size_t)r * Hn + h0) = pack4bf(vx * sc, vy * sc, vz * sc, vw * sc);
}

// ---------------------------------------------------------------------------
// Phase 3 block unit raw (0..511): causal relu prefix + fused RMSNorm,
// balanced tile remap.
// ---------------------------------------------------------------------------
#define ITILE 2
#define JCH   16
__device__ __forceinline__ void phase_bar(int raw, int h, const Ptrs& p, float* red)
{
  const int sel  = (raw < 256) ? raw : (511 - raw);
  const int bb   = raw >> 8;
  const int i0   = sel * ITILE;
  const size_t base = (size_t)bb * Tn * Hn;
  const us_t* __restrict__ bp = p.Bm + base + h;

  float av[ITILE], sum[ITILE];
  #pragma unroll
  for (int r = 0; r < ITILE; ++r) {
    av[r]  = bf2f(p.A[base + (size_t)(i0 + r) * Hn + h]);
    sum[r] = 0.f;
  }

  const int nfull = i0 & ~(JCH - 1);
  us_t b0[JCH], b1[JCH];

  #define LOADCH(buf, jj) { _Pragma("unroll") \
    for (int tt = 0; tt < JCH; ++tt) buf[tt] = bp[(size_t)((jj) + tt) * Hn]; }
  #define COMPCH(buf) { _Pragma("unroll") \
    for (int tt = 0; tt < JCH; ++tt) { float bv = bf2f(buf[tt]); _Pragma("unroll") \
      for (int r = 0; r < ITILE; ++r) sum[r] += fmaxf(av[r] + bv, 0.f); } }

  if (nfull > 0) {
    LOADCH(b0, 0);
    int j = 0;
    while (true) {
      const bool more1 = (j + JCH     < nfull);
      const bool more2 = (j + 2 * JCH < nfull);
      if (more1) LOADCH(b1, j + JCH);
      COMPCH(b0);
      j += JCH;
      if (!more1) break;
      if (more2) LOADCH(b0, j + JCH);
      COMPCH(b1);
      j += JCH;
      if (!more2) break;
    }
  }
  { // fixed-width predicated tail (in-bounds: nfull+15 <= 511)
    us_t bt[JCH];
    LOADCH(bt, nfull);
    const int lim = i0 - nfull;
    #pragma unroll
    for (int tt = 0; tt < JCH; ++tt) {
      float bv = bf2f(bt[tt]);
      #pragma unroll
      for (int r = 0; r < ITILE; ++r)
        sum[r] += (tt <= lim + r) ? fmaxf(av[r] + bv, 0.f) : 0.f;
    }
  }
  #undef LOADCH
  #undef COMPCH

  #pragma unroll
  for (int r = 0; r < ITILE; ++r) {
    float ss = block_reduce_sum_256(sum[r] * sum[r], red);
    float c  = (float)(i0 + r + 1);
    float sc = rsqrtf(ss * (1.0f / Hn) + EPSF * c * c);
    p.Yb[base + (size_t)(i0 + r) * Hn + h] = f2bf(sum[r] * sc);
  }
}

// ---------------------------------------------------------------------------
// Phase 4 wave unit wg (0..2047): out = x + Y @ w3 + b3, wave tile 16x32,
// K=256, LDS-free.
// ---------------------------------------------------------------------------
__device__ __forceinline__ void phase_out(int wg, int lane, const Ptrs& p)
{
  const int nt = wg & 31, mt = wg >> 5;
  const int m0 = mt * 16, n0 = nt * 32;
  const int lg = lane >> 4, lr = lane & 15;

  const us_t* ap  = p.Yb  + (size_t)(m0 + lr) * Hn + lg * 8;
  const us_t* bp0 = p.w3t + (size_t)(n0 + lr) * Hn + lg * 8;
  const us_t* bp1 = bp0 + 16 * Hn;

  f32x4 acc0 = {0.f,0.f,0.f,0.f}, acc1 = acc0;

  #pragma unroll 4
  for (int s = 0; s < 8; ++s) {
    bf16x8 a  = *(const bf16x8*)(ap  + s * 32);
    bf16x8 b0 = *(const bf16x8*)(bp0 + s * 32);
    bf16x8 b1 = *(const bf16x8*)(bp1 + s * 32);
    acc0 = MFMA16(a, b0, acc0);
    acc1 = MFMA16(a, b1, acc1);
  }

  const int row = m0 + lg * 4;
  const int c0 = n0 + lr, c1 = n0 + 16 + lr;
  const float bv0 = p.b3[c0], bv1 = p.b3[c1];
  #pragma unroll
  for (int i = 0; i < 4; ++i) {
    const size_t o0 = (size_t)(row + i) * En + c0;
    const size_t o1 = (size_t)(row + i) * En + c1;
    p.out[o0] = p.x[o0] + acc0[i] + bv0;
    p.out[o1] = p.x[o1] + acc1[i] + bv1;
  }
}

// ---------------------------------------------------------------------------
// Barrier-counter init (stream-ordered before the mega kernel each call).
// ---------------------------------------------------------------------------
__global__ void k_zero(u32_t* bar) {
  if (threadIdx.x < 8) bar[threadIdx.x] = 0u;
}

// ---------------------------------------------------------------------------
// Cooperative mega-kernel: 512 blocks x 256 thr, hand-rolled grid barriers.
// ---------------------------------------------------------------------------
__global__ __launch_bounds__(256, 2) void k_mega(Ptrs p)
{
  __shared__ float red[4];
  __shared__ float ts[32][33];
  const int blk = blockIdx.x, t = threadIdx.x;
  const int wid = t >> 6, lane = t & 63;

  for (int u = blk; u < 1792; u += 512) phase_prep(u, t, p, red, ts);
  gbar(p.bar + 0);
  phase_gemm(blk * 4 + wid, lane, p);
  gbar(p.bar + 1);
  phase_norm(blk * 4 + wid, lane, p);
  gbar(p.bar + 2);
  phase_bar(blk, t, p, red);
  gbar(p.bar + 3);
  phase_out(blk * 4 + wid, lane, p);
}

// ---------------------------------------------------------------------------
// Fallback discrete kernels (same device bodies) if cooperative launch fails.
// ---------------------------------------------------------------------------
__global__ __launch_bounds__(256) void k_prep_f(Ptrs p) {
  __shared__ float red[4];
  __shared__ float ts[32][33];
  phase_prep(blockIdx.x, threadIdx.x, p, red, ts);
}
__global__ __launch_bounds__(256) void k_gemm_f(Ptrs p) {
  phase_gemm(blockIdx.x * 4 + (threadIdx.x >> 6), threadIdx.x & 63, p);
}
__global__ __launch_bounds__(256) void k_norm_f(Ptrs p) {
  phase_norm(blockIdx.x * 4 + (threadIdx.x >> 6), threadIdx.x & 63, p);
}
__global__ __launch_bounds__(256) void k_bar_f(Ptrs p) {
  __shared__ float red[4];
  phase_bar(blockIdx.x, threadIdx.x, p, red);
}
__global__ __launch_bounds__(256) void k_out_f(Ptrs p) {
  phase_out(blockIdx.x * 4 + (threadIdx.x >> 6), threadIdx.x & 63, p);
}

// ---------------------------------------------------------------------------
extern "C" void kernel_launch(void* const* d_in, const int* in_sizes, int n_in,
                              void* d_out, int out_size, void* d_ws, size_t ws_size,
                              hipStream_t stream) {
  Ptrs p;
  p.x  = (const float*)d_in[0];
  p.w1 = (const float*)d_in[1];
  p.b1 = (const float*)d_in[2];
  p.w2 = (const float*)d_in[3];
  p.b2 = (const float*)d_in[4];
  p.w3 = (const float*)d_in[5];
  p.b3 = (const float*)d_in[6];
  p.out = (float*)d_out;

  char* q = (char*)d_ws;
  p.P   = (float*)q;   q += (size_t)4 * Mtot * 512 * 4;   // 8 MB
  p.xb  = (us_t*)q;    q += (size_t)Mtot * En * 2;        // 2 MB
  p.w1t = (us_t*)q;    q += (size_t)Hn * En * 2;
  p.w2t = (us_t*)q;    q += (size_t)Hn * En * 2;
  p.w3t = (us_t*)q;    q += (size_t)En * Hn * 2;
  p.A   = (us_t*)q;    q += (size_t)Mtot * Hn * 2;
  p.Bm  = (us_t*)q;    q += (size_t)Mtot * Hn * 2;
  p.Yb  = (us_t*)q;    q += (size_t)Mtot * Hn * 2;
  p.rs  = (float*)q;   q += (size_t)Mtot * 4;
  p.bar = (u32_t*)q;   q += 64;

  k_zero<<<1, 64, 0, stream>>>(p.bar);

  void* args[] = { (void*)&p };
  hipError_t e = hipLaunchCooperativeKernel((void*)k_mega, dim3(NBLK), dim3(256),
                                            args, 0, stream);
  if (e != hipSuccess) {
    k_prep_f<<<1792, 256, 0, stream>>>(p);
    k_gemm_f<<<512,  256, 0, stream>>>(p);
    k_norm_f<<<512,  256, 0, stream>>>(p);
    k_bar_f <<<512,  256, 0, stream>>>(p);
    k_out_f <<<512,  256, 0, stream>>>(p);
  }
}

// Round 7
// 47.642 us; speedup vs baseline: 7.6581x; 7.6581x over previous
//
#include <hip/hip_runtime.h>

#define EPSF 1e-6f
#define Bsz 2
#define Tn  512
#define En  1024
#define Hn  256
#define Mtot (Bsz * Tn)          // 1024 rows
typedef unsigned short us_t;
typedef unsigned int   u32_t;

typedef __attribute__((ext_vector_type(8))) short bf16x8;
typedef __attribute__((ext_vector_type(4))) float f32x4;
#define MFMA16(a, b, c) __builtin_amdgcn_mfma_f32_16x16x32_bf16((a), (b), (c), 0, 0, 0)

// ---------------------------------------------------------------------------
__device__ __forceinline__ us_t f2bf(float f) {
  union { float f; u32_t u; } x; x.f = f;
  u32_t r = (x.u + 0x7fffu + ((x.u >> 16) & 1u)) >> 16;   // RNE
  return (us_t)r;
}
__device__ __forceinline__ float bf2f(us_t u) {
  union { u32_t u; float f; } x; x.u = ((u32_t)u) << 16; return x.f;
}
__device__ __forceinline__ uint2 pack4bf(float a, float b, float c, float d) {
  uint2 r;
  r.x = (u32_t)f2bf(a) | ((u32_t)f2bf(b) << 16);
  r.y = (u32_t)f2bf(c) | ((u32_t)f2bf(d) << 16);
  return r;
}
__device__ __forceinline__ float block_reduce_sum_256(float v, float* smem) {
  #pragma unroll
  for (int off = 32; off > 0; off >>= 1) v += __shfl_down(v, off, 64);
  const int wave = threadIdx.x >> 6;
  if ((threadIdx.x & 63) == 0) smem[wave] = v;
  __syncthreads();
  float s = smem[0] + smem[1] + smem[2] + smem[3];
  __syncthreads();
  return s;
}

// ---------------------------------------------------------------------------
// K0 prep: blocks 0..255: cast 4 x-rows each (wave per row) + rowscale.
//          blocks 256..1023: transpose+cast one 32x32 tile of w1/w2/w3.
// 1024 blocks -> 4 blocks/CU.
// ---------------------------------------------------------------------------
__global__ __launch_bounds__(256) void k_prep(
    const float* __restrict__ x,
    const float* __restrict__ w1, const float* __restrict__ w2,
    const float* __restrict__ w3,
    us_t* __restrict__ xb, float* __restrict__ rs,
    us_t* __restrict__ w1t, us_t* __restrict__ w2t, us_t* __restrict__ w3t)
{
  const int b = blockIdx.x, t = threadIdx.x;

  if (b < 256) {
    const int wid = t >> 6, lane = t & 63;
    const int row = b * 4 + wid;
    const float4* xp = (const float4*)(x + (size_t)row * En);
    float4 v[4];
    #pragma unroll
    for (int i = 0; i < 4; ++i) v[i] = xp[lane + 64 * i];     // 4 indep loads
    float ss = 0.f;
    #pragma unroll
    for (int i = 0; i < 4; ++i)
      ss += v[i].x*v[i].x + v[i].y*v[i].y + v[i].z*v[i].z + v[i].w*v[i].w;
    #pragma unroll
    for (int off = 32; off > 0; off >>= 1) ss += __shfl_xor(ss, off, 64);
    if (lane == 0) rs[row] = rsqrtf(ss * (1.0f / En) + EPSF);
    uint2* xo = (uint2*)(xb + (size_t)row * En);
    #pragma unroll
    for (int i = 0; i < 4; ++i)
      xo[lane + 64 * i] = pack4bf(v[i].x, v[i].y, v[i].z, v[i].w);
    return;
  }

  __shared__ float ts[32][33];
  const int i = b - 256;
  const float* src; us_t* dst; int R, C, tr, tc;
  if (i < 256)      { src = w1; dst = w1t; R = 1024; C = 256;  tr = i >> 3;  tc = i & 7; }
  else if (i < 512) { int k = i - 256; src = w2; dst = w2t; R = 1024; C = 256; tr = k >> 3; tc = k & 7; }
  else              { int k = i - 512; src = w3; dst = w3t; R = 256; C = 1024; tr = k >> 5; tc = k & 31; }

  const int r = t >> 3, c4 = (t & 7) * 4;
  float4 v = *(const float4*)(src + (size_t)(tr * 32 + r) * C + tc * 32 + c4);
  ts[r][c4 + 0] = v.x; ts[r][c4 + 1] = v.y; ts[r][c4 + 2] = v.z; ts[r][c4 + 3] = v.w;
  __syncthreads();
  float o0 = ts[c4 + 0][r], o1 = ts[c4 + 1][r], o2 = ts[c4 + 2][r], o3 = ts[c4 + 3][r];
  *(uint2*)(dst + (size_t)(tc * 32 + r) * R + tr * 32 + c4) = pack4bf(o0, o1, o2, o3);
}

// ---------------------------------------------------------------------------
// K1 gemm: block = one 16x32 output tile, 4 waves = in-block split-K x4
// (each wave K=256, fully unrolled: 24 indep 64B loads + 16 MFMA).
// LDS combine -> Praw[1024][512] f32 (raw dot, no rs/bias).
// grid 1024 blocks (64 mt x 16 nt) -> 4 blocks/CU, 4 waves/SIMD.
// ---------------------------------------------------------------------------
__global__ __launch_bounds__(256, 4) void k_gemm(
    const us_t* __restrict__ xb,
    const us_t* __restrict__ w1t, const us_t* __restrict__ w2t,
    float* __restrict__ Praw)
{
  const int blk = blockIdx.x;
  const int mt = blk >> 4, nt = blk & 15;
  const int m0 = mt * 16, n0 = nt * 32;
  const int wid = threadIdx.x >> 6, lane = threadIdx.x & 63;
  const int lg = lane >> 4, lr = lane & 15;
  const int k0 = wid * 256;

  const us_t* ap = xb + (size_t)(m0 + lr) * En + k0 + lg * 8;
  const us_t* bbase = (n0 < Hn) ? (w1t + (size_t)n0 * En)
                                : (w2t + (size_t)(n0 - Hn) * En);
  const us_t* bp0 = bbase + (size_t)lr * En + k0 + lg * 8;
  const us_t* bp1 = bp0 + (size_t)16 * En;

  f32x4 acc0 = {0.f,0.f,0.f,0.f}, acc1 = acc0;

  #pragma unroll
  for (int s = 0; s < 8; ++s) {
    bf16x8 a  = *(const bf16x8*)(ap  + s * 32);
    bf16x8 b0 = *(const bf16x8*)(bp0 + s * 32);
    bf16x8 b1 = *(const bf16x8*)(bp1 + s * 32);
    acc0 = MFMA16(a, b0, acc0);
    acc1 = MFMA16(a, b1, acc1);
  }

  __shared__ float cmb[4][16][32];
  #pragma unroll
  for (int i = 0; i < 4; ++i) {
    cmb[wid][lg * 4 + i][lr]      = acc0[i];
    cmb[wid][lg * 4 + i][16 + lr] = acc1[i];
  }
  __syncthreads();

  #pragma unroll
  for (int e = 0; e < 2; ++e) {
    const int idx = threadIdx.x + e * 256;
    const int row = idx >> 5, col = idx & 31;
    float s = cmb[0][row][col] + cmb[1][row][col]
            + cmb[2][row][col] + cmb[3][row][col];
    Praw[(size_t)(m0 + row) * 512 + n0 + col] = s;
  }
}

// ---------------------------------------------------------------------------
// K2 norm: wave per row (2048 rows: which=0 -> A[T][H], which=1 -> BmT[H][T]).
// One float4/lane from combined Praw + rs + bias -> RMSNorm -> bf16.
// 512 blocks.
// ---------------------------------------------------------------------------
__global__ __launch_bounds__(256) void k_norm(
    const float* __restrict__ Praw, const float* __restrict__ rs,
    const float* __restrict__ b1, const float* __restrict__ b2,
    us_t* __restrict__ A, us_t* __restrict__ BmT)
{
  const int rw = blockIdx.x * 4 + (threadIdx.x >> 6);
  const int lane = threadIdx.x & 63;
  const int which = rw >> 10, r = rw & 1023;
  const int h0 = lane * 4;

  float4 d = *(const float4*)(Praw + (size_t)r * 512 + which * Hn + h0);
  const float s0 = rs[r];
  const float* bias = which ? b2 : b1;
  float4 bv = *(const float4*)(bias + h0);
  float vx = d.x * s0 + bv.x, vy = d.y * s0 + bv.y;
  float vz = d.z * s0 + bv.z, vw = d.w * s0 + bv.w;

  float ss = vx*vx + vy*vy + vz*vz + vw*vw;
  #pragma unroll
  for (int o2 = 32; o2 > 0; o2 >>= 1) ss += __shfl_xor(ss, o2, 64);
  const float sc = rsqrtf(ss * (1.0f / Hn) + EPSF);

  if (!which) {
    *(uint2*)(A + (size_t)r * Hn + h0) = pack4bf(vx*sc, vy*sc, vz*sc, vw*sc);
  } else {
    // transposed store: BmT[bb][h][t]
    const int bb = r >> 9, tcol = r & 511;
    us_t* bt = BmT + (size_t)bb * Hn * Tn + tcol;
    bt[(size_t)(h0 + 0) * Tn] = f2bf(vx * sc);
    bt[(size_t)(h0 + 1) * Tn] = f2bf(vy * sc);
    bt[(size_t)(h0 + 2) * Tn] = f2bf(vz * sc);
    bt[(size_t)(h0 + 3) * Tn] = f2bf(vw * sc);
  }
}

// ---------------------------------------------------------------------------
// K3 bar: thread h streams its OWN contiguous BmT row (bf16x8 = 8 j / 16B
// load, 4 loads = 32-j chunk, double-buffered). ITILE=2, 512 blocks,
// balanced remap. Fused exact RMSNorm (y = S * rsqrt(mean(S^2)+eps*c^2)).
// ---------------------------------------------------------------------------
#define JCHB 32
__global__ __launch_bounds__(256) void k_bar(
    const us_t* __restrict__ A, const us_t* __restrict__ BmT,
    us_t* __restrict__ Yb)
{
  const int raw = blockIdx.x;
  const int sel = (raw < 256) ? raw : (511 - raw);
  const int bb  = raw >> 8;
  const int i0  = sel * 2;
  const int h   = threadIdx.x;
  const size_t baseA = (size_t)bb * Tn * Hn;
  const us_t* __restrict__ bt = BmT + (size_t)bb * Hn * Tn + (size_t)h * Tn;

  float av0 = bf2f(A[baseA + (size_t)i0 * Hn + h]);
  float av1 = bf2f(A[baseA + (size_t)(i0 + 1) * Hn + h]);
  float sum0 = 0.f, sum1 = 0.f;

  const int nfull = i0 & ~(JCHB - 1);
  bf16x8 c0[4], c1[4];

  #define LOADC(dst, jj) { _Pragma("unroll") \
    for (int q = 0; q < 4; ++q) dst[q] = *(const bf16x8*)(bt + (jj) + q * 8); }
  #define PROCF(srcb) { _Pragma("unroll") \
    for (int q = 0; q < 4; ++q) { _Pragma("unroll") \
      for (int e = 0; e < 8; ++e) { \
        float bv = bf2f((us_t)srcb[q][e]); \
        sum0 += fmaxf(av0 + bv, 0.f); \
        sum1 += fmaxf(av1 + bv, 0.f); } } }

  if (nfull > 0) {
    LOADC(c0, 0);
    int j = 0;
    while (true) {
      const bool m1 = (j + JCHB     < nfull);
      const bool m2 = (j + 2 * JCHB < nfull);
      if (m1) LOADC(c1, j + JCHB);
      PROCF(c0);
      j += JCHB;
      if (!m1) break;
      if (m2) LOADC(c0, j + JCHB);
      PROCF(c1);
      j += JCHB;
      if (!m2) break;
    }
  }
  { // predicated tail chunk: j in [nfull, nfull+32), in-bounds (<=511)
    bf16x8 ct[4];
    LOADC(ct, nfull);
    const int lim = i0 - nfull;
    #pragma unroll
    for (int q = 0; q < 4; ++q)
      #pragma unroll
      for (int e = 0; e < 8; ++e) {
        const int jl = q * 8 + e;
        float bv = bf2f((us_t)ct[q][e]);
        sum0 += (jl <= lim)     ? fmaxf(av0 + bv, 0.f) : 0.f;
        sum1 += (jl <= lim + 1) ? fmaxf(av1 + bv, 0.f) : 0.f;
      }
  }
  #undef LOADC
  #undef PROCF

  __shared__ float red[4];
  {
    float ss = block_reduce_sum_256(sum0 * sum0, red);
    float c  = (float)(i0 + 1);
    float sc = rsqrtf(ss * (1.0f / Hn) + EPSF * c * c);
    Yb[baseA + (size_t)i0 * Hn + h] = f2bf(sum0 * sc);
  }
  {
    float ss = block_reduce_sum_256(sum1 * sum1, red);
    float c  = (float)(i0 + 2);
    float sc = rsqrtf(ss * (1.0f / Hn) + EPSF * c * c);
    Yb[baseA + (size_t)(i0 + 1) * Hn + h] = f2bf(sum1 * sc);
  }
}

// ---------------------------------------------------------------------------
// K4 out: out = x + Y @ w3 + b3.  Wave tile 16x32, K=256, LDS-free, fully
// unrolled (24 indep loads + 16 MFMA).  512 blocks x 4 waves.
// ---------------------------------------------------------------------------
__global__ __launch_bounds__(256, 4) void k_out(
    const us_t* __restrict__ Yb, const us_t* __restrict__ w3t,
    const float* __restrict__ x, const float* __restrict__ b3,
    float* __restrict__ out)
{
  const int wid = threadIdx.x >> 6, lane = threadIdx.x & 63;
  const int wg = blockIdx.x * 4 + wid;
  const int nt = wg & 31, mt = wg >> 5;
  const int m0 = mt * 16, n0 = nt * 32;
  const int lg = lane >> 4, lr = lane & 15;

  const us_t* ap  = Yb  + (size_t)(m0 + lr) * Hn + lg * 8;
  const us_t* bp0 = w3t + (size_t)(n0 + lr) * Hn + lg * 8;
  const us_t* bp1 = bp0 + (size_t)16 * Hn;

  f32x4 acc0 = {0.f,0.f,0.f,0.f}, acc1 = acc0;

  #pragma unroll
  for (int s = 0; s < 8; ++s) {
    bf16x8 a  = *(const bf16x8*)(ap  + s * 32);
    bf16x8 b0 = *(const bf16x8*)(bp0 + s * 32);
    bf16x8 b1 = *(const bf16x8*)(bp1 + s * 32);
    acc0 = MFMA16(a, b0, acc0);
    acc1 = MFMA16(a, b1, acc1);
  }

  const int row = m0 + lg * 4;
  const int c0 = n0 + lr, c1 = n0 + 16 + lr;
  const float bv0 = b3[c0], bv1 = b3[c1];
  #pragma unroll
  for (int i = 0; i < 4; ++i) {
    const size_t o0 = (size_t)(row + i) * En + c0;
    const size_t o1 = (size_t)(row + i) * En + c1;
    out[o0] = x[o0] + acc0[i] + bv0;
    out[o1] = x[o1] + acc1[i] + bv1;
  }
}

// ---------------------------------------------------------------------------
extern "C" void kernel_launch(void* const* d_in, const int* in_sizes, int n_in,
                              void* d_out, int out_size, void* d_ws, size_t ws_size,
                              hipStream_t stream) {
  const float* x  = (const float*)d_in[0];
  const float* w1 = (const float*)d_in[1];
  const float* b1 = (const float*)d_in[2];
  const float* w2 = (const float*)d_in[3];
  const float* b2 = (const float*)d_in[4];
  const float* w3 = (const float*)d_in[5];
  const float* b3 = (const float*)d_in[6];
  float* out = (float*)d_out;

  char* q = (char*)d_ws;
  float* Praw = (float*)q;  q += (size_t)Mtot * 512 * 4;   // 2 MB
  us_t* xb    = (us_t*)q;   q += (size_t)Mtot * En * 2;    // 2 MB
  us_t* w1t   = (us_t*)q;   q += (size_t)Hn * En * 2;
  us_t* w2t   = (us_t*)q;   q += (size_t)Hn * En * 2;
  us_t* w3t   = (us_t*)q;   q += (size_t)En * Hn * 2;
  us_t* A     = (us_t*)q;   q += (size_t)Mtot * Hn * 2;
  us_t* BmT   = (us_t*)q;   q += (size_t)Mtot * Hn * 2;
  us_t* Yb    = (us_t*)q;   q += (size_t)Mtot * Hn * 2;
  float* rs   = (float*)q;  q += (size_t)Mtot * 4;

  k_prep<<<1024, 256, 0, stream>>>(x, w1, w2, w3, xb, rs, w1t, w2t, w3t);
  k_gemm<<<1024, 256, 0, stream>>>(xb, w1t, w2t, Praw);
  k_norm<<<512,  256, 0, stream>>>(Praw, rs, b1, b2, A, BmT);
  k_bar <<<512,  256, 0, stream>>>(A, BmT, Yb);
  k_out <<<512,  256, 0, stream>>>(Yb, w3t, x, b3, out);
}

// Round 8
// 46.718 us; speedup vs baseline: 7.8095x; 1.0198x over previous
//
#include <hip/hip_runtime.h>

#define EPSF 1e-6f
#define Bsz 2
#define Tn  512
#define En  1024
#define Hn  256
#define Mtot (Bsz * Tn)          // 1024 rows
typedef unsigned short us_t;
typedef unsigned int   u32_t;

typedef __attribute__((ext_vector_type(8))) short bf16x8;
typedef __attribute__((ext_vector_type(4))) float f32x4;
#define MFMA16(a, b, c) __builtin_amdgcn_mfma_f32_16x16x32_bf16((a), (b), (c), 0, 0, 0)

// ---------------------------------------------------------------------------
__device__ __forceinline__ us_t f2bf(float f) {
  union { float f; u32_t u; } x; x.f = f;
  u32_t r = (x.u + 0x7fffu + ((x.u >> 16) & 1u)) >> 16;   // RNE
  return (us_t)r;
}
__device__ __forceinline__ float bf2f(us_t u) {
  union { u32_t u; float f; } x; x.u = ((u32_t)u) << 16; return x.f;
}
__device__ __forceinline__ uint2 pack4bf(float a, float b, float c, float d) {
  uint2 r;
  r.x = (u32_t)f2bf(a) | ((u32_t)f2bf(b) << 16);
  r.y = (u32_t)f2bf(c) | ((u32_t)f2bf(d) << 16);
  return r;
}
__device__ __forceinline__ float block_reduce_sum_256(float v, float* smem) {
  #pragma unroll
  for (int off = 32; off > 0; off >>= 1) v += __shfl_down(v, off, 64);
  const int wave = threadIdx.x >> 6;
  if ((threadIdx.x & 63) == 0) smem[wave] = v;
  __syncthreads();
  float s = smem[0] + smem[1] + smem[2] + smem[3];
  __syncthreads();
  return s;
}

// ---------------------------------------------------------------------------
// K0 prep: blocks 0..255: cast 4 x-rows each (wave per row) + rowscale.
//          blocks 256..1023: transpose+cast one 32x32 tile of w1/w2/w3.
// ---------------------------------------------------------------------------
__global__ __launch_bounds__(256) void k_prep(
    const float* __restrict__ x,
    const float* __restrict__ w1, const float* __restrict__ w2,
    const float* __restrict__ w3,
    us_t* __restrict__ xb, float* __restrict__ rs,
    us_t* __restrict__ w1t, us_t* __restrict__ w2t, us_t* __restrict__ w3t)
{
  const int b = blockIdx.x, t = threadIdx.x;

  if (b < 256) {
    const int wid = t >> 6, lane = t & 63;
    const int row = b * 4 + wid;
    const float4* xp = (const float4*)(x + (size_t)row * En);
    float4 v[4];
    #pragma unroll
    for (int i = 0; i < 4; ++i) v[i] = xp[lane + 64 * i];     // 4 indep loads
    float ss = 0.f;
    #pragma unroll
    for (int i = 0; i < 4; ++i)
      ss += v[i].x*v[i].x + v[i].y*v[i].y + v[i].z*v[i].z + v[i].w*v[i].w;
    #pragma unroll
    for (int off = 32; off > 0; off >>= 1) ss += __shfl_xor(ss, off, 64);
    if (lane == 0) rs[row] = rsqrtf(ss * (1.0f / En) + EPSF);
    uint2* xo = (uint2*)(xb + (size_t)row * En);
    #pragma unroll
    for (int i = 0; i < 4; ++i)
      xo[lane + 64 * i] = pack4bf(v[i].x, v[i].y, v[i].z, v[i].w);
    return;
  }

  __shared__ float ts[32][33];
  const int i = b - 256;
  const float* src; us_t* dst; int R, C, tr, tc;
  if (i < 256)      { src = w1; dst = w1t; R = 1024; C = 256;  tr = i >> 3;  tc = i & 7; }
  else if (i < 512) { int k = i - 256; src = w2; dst = w2t; R = 1024; C = 256; tr = k >> 3; tc = k & 7; }
  else              { int k = i - 512; src = w3; dst = w3t; R = 256; C = 1024; tr = k >> 5; tc = k & 31; }

  const int r = t >> 3, c4 = (t & 7) * 4;
  float4 v = *(const float4*)(src + (size_t)(tr * 32 + r) * C + tc * 32 + c4);
  ts[r][c4 + 0] = v.x; ts[r][c4 + 1] = v.y; ts[r][c4 + 2] = v.z; ts[r][c4 + 3] = v.w;
  __syncthreads();
  float o0 = ts[c4 + 0][r], o1 = ts[c4 + 1][r], o2 = ts[c4 + 2][r], o3 = ts[c4 + 3][r];
  *(uint2*)(dst + (size_t)(tc * 32 + r) * R + tr * 32 + c4) = pack4bf(o0, o1, o2, o3);
}

// ---------------------------------------------------------------------------
// K1 gemm: block = one 16x32 output tile, 4 waves = in-block split-K x4.
// LDS combine -> Praw[1024][512] f32.  1024 blocks (unchanged from R7).
// ---------------------------------------------------------------------------
__global__ __launch_bounds__(256, 4) void k_gemm(
    const us_t* __restrict__ xb,
    const us_t* __restrict__ w1t, const us_t* __restrict__ w2t,
    float* __restrict__ Praw)
{
  const int blk = blockIdx.x;
  const int mt = blk >> 4, nt = blk & 15;
  const int m0 = mt * 16, n0 = nt * 32;
  const int wid = threadIdx.x >> 6, lane = threadIdx.x & 63;
  const int lg = lane >> 4, lr = lane & 15;
  const int k0 = wid * 256;

  const us_t* ap = xb + (size_t)(m0 + lr) * En + k0 + lg * 8;
  const us_t* bbase = (n0 < Hn) ? (w1t + (size_t)n0 * En)
                                : (w2t + (size_t)(n0 - Hn) * En);
  const us_t* bp0 = bbase + (size_t)lr * En + k0 + lg * 8;
  const us_t* bp1 = bp0 + (size_t)16 * En;

  f32x4 acc0 = {0.f,0.f,0.f,0.f}, acc1 = acc0;

  #pragma unroll
  for (int s = 0; s < 8; ++s) {
    bf16x8 a  = *(const bf16x8*)(ap  + s * 32);
    bf16x8 b0 = *(const bf16x8*)(bp0 + s * 32);
    bf16x8 b1 = *(const bf16x8*)(bp1 + s * 32);
    acc0 = MFMA16(a, b0, acc0);
    acc1 = MFMA16(a, b1, acc1);
  }

  __shared__ float cmb[4][16][32];
  #pragma unroll
  for (int i = 0; i < 4; ++i) {
    cmb[wid][lg * 4 + i][lr]      = acc0[i];
    cmb[wid][lg * 4 + i][16 + lr] = acc1[i];
  }
  __syncthreads();

  #pragma unroll
  for (int e = 0; e < 2; ++e) {
    const int idx = threadIdx.x + e * 256;
    const int row = idx >> 5, col = idx & 31;
    float s = cmb[0][row][col] + cmb[1][row][col]
            + cmb[2][row][col] + cmb[3][row][col];
    Praw[(size_t)(m0 + row) * 512 + n0 + col] = s;
  }
}

// ---------------------------------------------------------------------------
// K2 norm:
//  blocks 0..255  (a-half): 4 rows each, wave-per-row, row-major A write.
//  blocks 256..319 (b-half): 16 rows each; normalize into LDS, then
//  TRANSPOSE-GATHER store: thread h writes BmT[h][r0..r0+15] as 2x16B —
//  full-line writes instead of R7's 2B-at-1KB-stride scalar RMWs.
// ---------------------------------------------------------------------------
__global__ __launch_bounds__(256) void k_norm(
    const float* __restrict__ Praw, const float* __restrict__ rs,
    const float* __restrict__ b1, const float* __restrict__ b2,
    us_t* __restrict__ A, us_t* __restrict__ BmT)
{
  const int blk = blockIdx.x, t = threadIdx.x;

  if (blk < 256) {                 // ---- a-half: wave per row (as R7) ----
    const int r = blk * 4 + (t >> 6);
    const int lane = t & 63;
    const int h0 = lane * 4;

    float4 d = *(const float4*)(Praw + (size_t)r * 512 + h0);
    const float s0 = rs[r];
    float4 bv = *(const float4*)(b1 + h0);
    float vx = d.x * s0 + bv.x, vy = d.y * s0 + bv.y;
    float vz = d.z * s0 + bv.z, vw = d.w * s0 + bv.w;

    float ss = vx*vx + vy*vy + vz*vz + vw*vw;
    #pragma unroll
    for (int o2 = 32; o2 > 0; o2 >>= 1) ss += __shfl_xor(ss, o2, 64);
    const float sc = rsqrtf(ss * (1.0f / Hn) + EPSF);
    *(uint2*)(A + (size_t)r * Hn + h0) = pack4bf(vx*sc, vy*sc, vz*sc, vw*sc);
    return;
  }

  // ---- b-half: 16 rows per block ----
  __shared__ us_t ls[16][256];     // 8 KB
  const int r0  = (blk - 256) * 16;            // global b-row 0..1023, 16-aligned
  const int row = t >> 4;                      // 0..15 (local row)
  const int c0  = (t & 15) * 16;               // 16 cols per thread
  const int r   = r0 + row;

  float v[16];
  float ss = 0.f;
  const float s0 = rs[r];
  #pragma unroll
  for (int q = 0; q < 4; ++q) {
    float4 d  = *(const float4*)(Praw + (size_t)r * 512 + Hn + c0 + q * 4);
    float4 bv = *(const float4*)(b2 + c0 + q * 4);
    v[q*4+0] = d.x * s0 + bv.x;  v[q*4+1] = d.y * s0 + bv.y;
    v[q*4+2] = d.z * s0 + bv.z;  v[q*4+3] = d.w * s0 + bv.w;
  }
  #pragma unroll
  for (int k = 0; k < 16; ++k) ss += v[k] * v[k];
  #pragma unroll
  for (int o2 = 1; o2 < 16; o2 <<= 1) ss += __shfl_xor(ss, o2, 64);
  const float sc = rsqrtf(ss * (1.0f / Hn) + EPSF);

  uint2 p0 = pack4bf(v[0]*sc,  v[1]*sc,  v[2]*sc,  v[3]*sc);
  uint2 p1 = pack4bf(v[4]*sc,  v[5]*sc,  v[6]*sc,  v[7]*sc);
  uint2 p2 = pack4bf(v[8]*sc,  v[9]*sc,  v[10]*sc, v[11]*sc);
  uint2 p3 = pack4bf(v[12]*sc, v[13]*sc, v[14]*sc, v[15]*sc);
  *(uint2*)&ls[row][c0 + 0]  = p0;
  *(uint2*)&ls[row][c0 + 4]  = p1;
  *(uint2*)&ls[row][c0 + 8]  = p2;
  *(uint2*)&ls[row][c0 + 12] = p3;
  __syncthreads();

  // transpose-gather: thread h = t packs column h of ls (16 rows)
  const int h = t;
  us_t col[16];
  #pragma unroll
  for (int j = 0; j < 16; ++j) col[j] = ls[j][h];   // 2 lanes/bank: free
  u32_t w[8];
  #pragma unroll
  for (int k = 0; k < 8; ++k)
    w[k] = (u32_t)col[2*k] | ((u32_t)col[2*k+1] << 16);

  const int bb   = r0 >> 9;            // batch
  const int tcol = r0 & 511;
  us_t* bt = BmT + (size_t)bb * Hn * Tn + (size_t)h * Tn + tcol;
  ((uint4*)bt)[0] = make_uint4(w[0], w[1], w[2], w[3]);
  ((uint4*)bt)[1] = make_uint4(w[4], w[5], w[6], w[7]);
}

// ---------------------------------------------------------------------------
// K3 bar: thread h streams its OWN contiguous BmT row.  Unchanged from R7.
// ---------------------------------------------------------------------------
#define JCHB 32
__global__ __launch_bounds__(256) void k_bar(
    const us_t* __restrict__ A, const us_t* __restrict__ BmT,
    us_t* __restrict__ Yb)
{
  const int raw = blockIdx.x;
  const int sel = (raw < 256) ? raw : (511 - raw);
  const int bb  = raw >> 8;
  const int i0  = sel * 2;
  const int h   = threadIdx.x;
  const size_t baseA = (size_t)bb * Tn * Hn;
  const us_t* __restrict__ bt = BmT + (size_t)bb * Hn * Tn + (size_t)h * Tn;

  float av0 = bf2f(A[baseA + (size_t)i0 * Hn + h]);
  float av1 = bf2f(A[baseA + (size_t)(i0 + 1) * Hn + h]);
  float sum0 = 0.f, sum1 = 0.f;

  const int nfull = i0 & ~(JCHB - 1);
  bf16x8 c0[4], c1[4];

  #define LOADC(dst, jj) { _Pragma("unroll") \
    for (int q = 0; q < 4; ++q) dst[q] = *(const bf16x8*)(bt + (jj) + q * 8); }
  #define PROCF(srcb) { _Pragma("unroll") \
    for (int q = 0; q < 4; ++q) { _Pragma("unroll") \
      for (int e = 0; e < 8; ++e) { \
        float bv = bf2f((us_t)srcb[q][e]); \
        sum0 += fmaxf(av0 + bv, 0.f); \
        sum1 += fmaxf(av1 + bv, 0.f); } } }

  if (nfull > 0) {
    LOADC(c0, 0);
    int j = 0;
    while (true) {
      const bool m1 = (j + JCHB     < nfull);
      const bool m2 = (j + 2 * JCHB < nfull);
      if (m1) LOADC(c1, j + JCHB);
      PROCF(c0);
      j += JCHB;
      if (!m1) break;
      if (m2) LOADC(c0, j + JCHB);
      PROCF(c1);
      j += JCHB;
      if (!m2) break;
    }
  }
  { // predicated tail chunk: j in [nfull, nfull+32), in-bounds (<=511)
    bf16x8 ct[4];
    LOADC(ct, nfull);
    const int lim = i0 - nfull;
    #pragma unroll
    for (int q = 0; q < 4; ++q)
      #pragma unroll
      for (int e = 0; e < 8; ++e) {
        const int jl = q * 8 + e;
        float bv = bf2f((us_t)ct[q][e]);
        sum0 += (jl <= lim)     ? fmaxf(av0 + bv, 0.f) : 0.f;
        sum1 += (jl <= lim + 1) ? fmaxf(av1 + bv, 0.f) : 0.f;
      }
  }
  #undef LOADC
  #undef PROCF

  __shared__ float red[4];
  {
    float ss = block_reduce_sum_256(sum0 * sum0, red);
    float c  = (float)(i0 + 1);
    float sc = rsqrtf(ss * (1.0f / Hn) + EPSF * c * c);
    Yb[baseA + (size_t)i0 * Hn + h] = f2bf(sum0 * sc);
  }
  {
    float ss = block_reduce_sum_256(sum1 * sum1, red);
    float c  = (float)(i0 + 2);
    float sc = rsqrtf(ss * (1.0f / Hn) + EPSF * c * c);
    Yb[baseA + (size_t)(i0 + 1) * Hn + h] = f2bf(sum1 * sc);
  }
}

// ---------------------------------------------------------------------------
// K4 out: out = x + Y @ w3 + b3.  Unchanged from R7.
// ---------------------------------------------------------------------------
__global__ __launch_bounds__(256, 4) void k_out(
    const us_t* __restrict__ Yb, const us_t* __restrict__ w3t,
    const float* __restrict__ x, const float* __restrict__ b3,
    float* __restrict__ out)
{
  const int wid = threadIdx.x >> 6, lane = threadIdx.x & 63;
  const int wg = blockIdx.x * 4 + wid;
  const int nt = wg & 31, mt = wg >> 5;
  const int m0 = mt * 16, n0 = nt * 32;
  const int lg = lane >> 4, lr = lane & 15;

  const us_t* ap  = Yb  + (size_t)(m0 + lr) * Hn + lg * 8;
  const us_t* bp0 = w3t + (size_t)(n0 + lr) * Hn + lg * 8;
  const us_t* bp1 = bp0 + (size_t)16 * Hn;

  f32x4 acc0 = {0.f,0.f,0.f,0.f}, acc1 = acc0;

  #pragma unroll
  for (int s = 0; s < 8; ++s) {
    bf16x8 a  = *(const bf16x8*)(ap  + s * 32);
    bf16x8 b0 = *(const bf16x8*)(bp0 + s * 32);
    bf16x8 b1 = *(const bf16x8*)(bp1 + s * 32);
    acc0 = MFMA16(a, b0, acc0);
    acc1 = MFMA16(a, b1, acc1);
  }

  const int row = m0 + lg * 4;
  const int c0 = n0 + lr, c1 = n0 + 16 + lr;
  const float bv0 = b3[c0], bv1 = b3[c1];
  #pragma unroll
  for (int i = 0; i < 4; ++i) {
    const size_t o0 = (size_t)(row + i) * En + c0;
    const size_t o1 = (size_t)(row + i) * En + c1;
    out[o0] = x[o0] + acc0[i] + bv0;
    out[o1] = x[o1] + acc1[i] + bv1;
  }
}

// ---------------------------------------------------------------------------
extern "C" void kernel_launch(void* const* d_in, const int* in_sizes, int n_in,
                              void* d_out, int out_size, void* d_ws, size_t ws_size,
                              hipStream_t stream) {
  const float* x  = (const float*)d_in[0];
  const float* w1 = (const float*)d_in[1];
  const float* b1 = (const float*)d_in[2];
  const float* w2 = (const float*)d_in[3];
  const float* b2 = (const float*)d_in[4];
  const float* w3 = (const float*)d_in[5];
  const float* b3 = (const float*)d_in[6];
  float* out = (float*)d_out;

  char* q = (char*)d_ws;
  float* Praw = (float*)q;  q += (size_t)Mtot * 512 * 4;   // 2 MB
  us_t* xb    = (us_t*)q;   q += (size_t)Mtot * En * 2;    // 2 MB
  us_t* w1t   = (us_t*)q;   q += (size_t)Hn * En * 2;
  us_t* w2t   = (us_t*)q;   q += (size_t)Hn * En * 2;
  us_t* w3t   = (us_t*)q;   q += (size_t)En * Hn * 2;
  us_t* A     = (us_t*)q;   q += (size_t)Mtot * Hn * 2;
  us_t* BmT   = (us_t*)q;   q += (size_t)Mtot * Hn * 2;
  us_t* Yb    = (us_t*)q;   q += (size_t)Mtot * Hn * 2;
  float* rs   = (float*)q;  q += (size_t)Mtot * 4;

  k_prep<<<1024, 256, 0, stream>>>(x, w1, w2, w3, xb, rs, w1t, w2t, w3t);
  k_gemm<<<1024, 256, 0, stream>>>(xb, w1t, w2t, Praw);
  k_norm<<<320,  256, 0, stream>>>(Praw, rs, b1, b2, A, BmT);
  k_bar <<<512,  256, 0, stream>>>(A, BmT, Yb);
  k_out <<<512,  256, 0, stream>>>(Yb, w3t, x, b3, out);
}